// Round 6
// baseline (15916.736 us; speedup 1.0000x reference)
//
#include <hip/hip_runtime.h>

#define T_STEPS 1024
#define N_IN    128
#define H       256
#define N_OUT   64
#define WARM    10

// In-order ascending-j sparse sum, SINGLE accumulator, plain adds.
// Bit-identical to numpy's k-sequential FMA chain over all 256 terms,
// because skipped terms contribute FMA(0.0, w, a) == a exactly.
__device__ __forceinline__ float walk(const unsigned long long* __restrict__ m4,
                                      const float* __restrict__ base,
                                      int sj, int si, int i) {
  float a = 0.f;
#pragma unroll
  for (int w = 0; w < 4; ++w) {
    unsigned long long m = m4[w];          // LDS broadcast (block-uniform)
    const float* bp = base + (size_t)(w * 64) * sj + (size_t)i * si;
    while (m) {
      int j = __ffsll((unsigned long long)m) - 1;
      m &= m - 1;
      a += bp[(size_t)j * sj];             // ascending j within word, words ascending
    }
  }
  return a;
}

// ---------- prep: transpose all weight matrices into ws ----------
// ws floats: [0,32768) WinT[k][i]   | [32768,98304)  Wh1T[j][i]
//            [98304,163840) W12T    | [163840,229376) Wh2T
//            [229376,245760) WoutT[j][o]
__global__ void srnn_prep(const float* __restrict__ Win,
                          const float* __restrict__ Wh1,
                          const float* __restrict__ W12,
                          const float* __restrict__ Wh2,
                          const float* __restrict__ Wout,
                          float* __restrict__ ws) {
  int idx = blockIdx.x * 256 + (int)threadIdx.x;     // 0 .. 245759
  if (idx < 32768) {
    int k = idx >> 8, i = idx & 255;
    ws[idx] = Win[i * N_IN + k];                     // WinT[k][i]
  } else if (idx < 229376) {
    int rem = idx - 32768;
    int mat = rem >> 16;
    int r2  = rem & 65535;
    int j = r2 >> 8, i = r2 & 255;
    const float* src = (mat == 0) ? Wh1 : (mat == 1) ? W12 : Wh2;
    ws[idx] = src[i * H + j];                        // WT[j][i]
  } else {
    int rem = idx - 229376;
    int j = rem >> 6, o = rem & 63;
    ws[idx] = Wout[o * H + j];                       // WoutT[j][o]
  }
}

// ---------- faithful-f32-order scan: 1 block (1024 thr) per batch row ----------
__launch_bounds__(1024)
__global__ void srnn_scan(const float* __restrict__ x,
                          const float* __restrict__ Win, int wsj, int wsi,
                          const float* __restrict__ bin_p,
                          const float* __restrict__ bh1_p,
                          const float* __restrict__ b12_p,
                          const float* __restrict__ bh2_p,
                          const float* __restrict__ Wh1, int h1j, int h1i,
                          const float* __restrict__ W12m, int c12j, int c12i,
                          const float* __restrict__ Wh2, int h2j, int h2i,
                          const float* __restrict__ Wo,  int woj, int woi,
                          const float* __restrict__ bo_p,
                          float* __restrict__ out) {
  __shared__ float xs[2][N_IN];
  __shared__ float xw[H], h1d[H], h2d[H], c12[H];
  __shared__ unsigned long long s1m[4], s2m[4];

  const int tid = (int)threadIdx.x;
  const int g   = tid >> 8;        // group 0..3
  const int i   = tid & 255;
  const int b   = (int)blockIdx.x;

  // Per-role constants (hoisted loads)
  const float bin_i = (tid < H) ? bin_p[i] : 0.f;
  const float bh1_i = (tid < H) ? bh1_p[i] : 0.f;
  const float b12_i = (tid < H) ? b12_p[i] : 0.f;
  const float bh2_i = (tid < H) ? bh2_p[i] : 0.f;
  const float bo_o  = (g == 3 && i < N_OUT) ? bo_p[i] : 0.f;

  if (tid < 4) s1m[tid] = 0ull;
  else if (tid < 8) s2m[tid - 4] = 0ull;
  if (tid < N_IN) xs[0][tid] = x[(size_t)b * (T_STEPS * N_IN) + tid];

  float m1 = 0.f, m2 = 0.f, acc = 0.f;

  __syncthreads();

  for (int t = 0; t < T_STEPS; ++t) {
    const int cur = t & 1;

    // ---- Phase 1: x-dot | h1-gather | h2-gather | readout(t-1) + x-prefetch
    if (g == 0) {
      // Sequential k=0..127, single accumulator, FMA — numpy sgemm per-element order.
      float a = 0.f;
      const float* wp = Win + (size_t)i * wsi;
#pragma unroll 16
      for (int k = 0; k < N_IN; ++k)
        a = fmaf(xs[cur][k], wp[(size_t)k * wsj], a);
      xw[i] = a;
    } else if (g == 1) {
      h1d[i] = walk(s1m, Wh1, h1j, h1i, i);
    } else if (g == 2) {
      h2d[i] = walk(s2m, Wh2, h2j, h2i, i);
    } else {
      if (i < N_OUT) {
        if (t - 1 >= WARM) {                 // readout for step t-1 (s2m = s2(t-1))
          float d = walk(s2m, Wo, woj, woi, i);
          acc = acc + (d + bo_o);            // np order: (dot + b_out), then acc+
        }
      } else if (i >= 128 && t + 1 < T_STEPS) {
        int k = i - 128;
        xs[cur ^ 1][k] = x[(size_t)b * (T_STEPS * N_IN) + (size_t)(t + 1) * N_IN + k];
      }
    }
    __syncthreads();

    // ---- Phase 2: layer-1 membrane + spike (left-to-right np chain)
    if (tid < H) {
      float u1 = 0.9f * m1;
      u1 = u1 + xw[i];
      u1 = u1 + bin_i;
      u1 = u1 + h1d[i];
      u1 = u1 + bh1_i;
      bool sp = (u1 - 1.0f) > 0.0f;
      m1 = u1 - (sp ? 1.0f : 0.0f);
      unsigned long long bm = __ballot(sp);
      if ((tid & 63) == 0) s1m[tid >> 6] = bm;
    }
    __syncthreads();

    // ---- Phase 3: W_12 gather with SAME-step s1
    if (tid < H) c12[i] = walk(s1m, W12m, c12j, c12i, i);
    __syncthreads();

    // ---- Phase 4: layer-2 membrane + spike
    if (tid < H) {
      float u2 = 0.9f * m2;
      u2 = u2 + c12[i];
      u2 = u2 + b12_i;
      u2 = u2 + h2d[i];
      u2 = u2 + bh2_i;
      bool sp = (u2 - 1.0f) > 0.0f;
      m2 = u2 - (sp ? 1.0f : 0.0f);
      unsigned long long bm = __ballot(sp);
      if ((tid & 63) == 0) s2m[tid >> 6] = bm;
    }
    __syncthreads();
  }

  // ---- final readout for t = 1023, then output
  if (g == 3 && i < N_OUT) {
    float d = walk(s2m, Wo, woj, woi, i);
    acc = acc + (d + bo_o);
    out[(size_t)b * N_OUT + i] = acc / 1014.0f;   // f32 divide, like np
  }
}

// ---------- launch ----------
extern "C" void kernel_launch(void* const* d_in, const int* in_sizes, int n_in,
                              void* d_out, int out_size, void* d_ws, size_t ws_size,
                              hipStream_t stream) {
  const float* x     = (const float*)d_in[0];
  const float* W_in  = (const float*)d_in[1];
  const float* b_in  = (const float*)d_in[2];
  const float* W_h1  = (const float*)d_in[3];
  const float* b_h1  = (const float*)d_in[4];
  const float* W_12  = (const float*)d_in[5];
  const float* b_12  = (const float*)d_in[6];
  const float* W_h2  = (const float*)d_in[7];
  const float* b_h2  = (const float*)d_in[8];
  const float* W_out = (const float*)d_in[9];
  const float* b_out = (const float*)d_in[10];
  float* out = (float*)d_out;
  float* wsf = (float*)d_ws;

  const int total = 128 * 256 + 3 * 256 * 256 + 256 * 64;   // 245760 floats
  const bool use_t = (ws_size >= (size_t)total * sizeof(float));

  const float *WinA, *Wh1A, *W12A, *Wh2A, *WoA;
  int wsj, wsi, h1j, h1i, c12j, c12i, h2j, h2i, woj, woi;
  if (use_t) {
    srnn_prep<<<total / 256, 256, 0, stream>>>(W_in, W_h1, W_12, W_h2, W_out, wsf);
    WinA = wsf;                 wsj = 256; wsi = 1;     // WinT[k][i]
    Wh1A = wsf + 32768;         h1j = 256; h1i = 1;     // Wh1T[j][i]
    W12A = wsf + 98304;         c12j = 256; c12i = 1;
    Wh2A = wsf + 163840;        h2j = 256; h2i = 1;
    WoA  = wsf + 229376;        woj = 64;  woi = 1;     // WoutT[j][o]
  } else {
    WinA = W_in;   wsj = 1;  wsi = 128;                 // original layouts
    Wh1A = W_h1;   h1j = 1;  h1i = 256;
    W12A = W_12;   c12j = 1; c12i = 256;
    Wh2A = W_h2;   h2j = 1;  h2i = 256;
    WoA  = W_out;  woj = 1;  woi = 256;
  }

  srnn_scan<<<256, 1024, 0, stream>>>(x, WinA, wsj, wsi,
                                      b_in, b_h1, b_12, b_h2,
                                      Wh1A, h1j, h1i, W12A, c12j, c12i,
                                      Wh2A, h2j, h2i, WoA, woj, woi,
                                      b_out, out);
}

// Round 7
// 6636.943 us; speedup vs baseline: 2.3982x; 2.3982x over previous
//
#include <hip/hip_runtime.h>

#define T_STEPS 1024
#define N_IN    128
#define H       256
#define N_OUT   64
#define WARM    10

// Batched in-order sparse sum. Bit-identical to the single-accumulator
// ascending-j chain (== numpy's per-element sgemm order): tail slots add
// literal +0.0f, which is an exact identity (the accumulator can never be
// -0.0: it starts at +0.0 and no sum of reals rounds to -0.0).
// Mask words are block-uniform (read from LDS broadcast) -> all branches
// and selects are wave-uniform; the 16 loads per batch are independent and
// issue together, hiding L2 latency that previously serialized per-element.
__device__ __forceinline__ float walk16(const unsigned long long* __restrict__ m4,
                                        const float* __restrict__ base,
                                        int sjj, int sii, int i) {
  float a = 0.f;
#pragma unroll
  for (int w = 0; w < 4; ++w) {
    unsigned long long m = m4[w];
    const float* bp = base + (size_t)(w * 64) * sjj + (size_t)i * sii;
    while (m) {
      float t0,t1,t2,t3,t4,t5,t6,t7,t8,t9,t10,t11,t12,t13,t14,t15;
#define GRAB(tk) { int j = m ? (__ffsll(m) - 1) : 0;            \
                   float v = bp[(size_t)j * sjj];               \
                   tk = m ? v : 0.0f;                           \
                   m &= m - 1; }
      GRAB(t0)  GRAB(t1)  GRAB(t2)  GRAB(t3)
      GRAB(t4)  GRAB(t5)  GRAB(t6)  GRAB(t7)
      GRAB(t8)  GRAB(t9)  GRAB(t10) GRAB(t11)
      GRAB(t12) GRAB(t13) GRAB(t14) GRAB(t15)
#undef GRAB
      a += t0;  a += t1;  a += t2;  a += t3;
      a += t4;  a += t5;  a += t6;  a += t7;
      a += t8;  a += t9;  a += t10; a += t11;
      a += t12; a += t13; a += t14; a += t15;
    }
  }
  return a;
}

// ---------- prep: transpose W_h1, W_12, W_h2 (HxH) and W_out (OUTxH) into ws
// ws floats: [0,65536) Wh1T | [65536,131072) W12T | [131072,196608) Wh2T
//            [196608,212992) WoutT  (WoutT[j][o] = W_out[o][j])
__global__ void srnn_prep(const float* __restrict__ Wh1,
                          const float* __restrict__ W12,
                          const float* __restrict__ Wh2,
                          const float* __restrict__ Wout,
                          float* __restrict__ ws) {
  int idx = blockIdx.x * 256 + (int)threadIdx.x;     // 0 .. 212991
  if (idx < 3 * H * H) {
    int mat = idx >> 16;
    int rem = idx & (H * H - 1);
    int j = rem >> 8;                  // source column
    int i = rem & (H - 1);             // source row
    const float* src = (mat == 0) ? Wh1 : (mat == 1) ? W12 : Wh2;
    ws[idx] = src[i * H + j];          // WT[j][i] = W[i][j]
  } else {
    int rem = idx - 3 * H * H;         // 0 .. 16383
    int j = rem >> 6;
    int o = rem & (N_OUT - 1);
    ws[idx] = Wout[o * H + j];         // WoutT[j][o]
  }
}

// ---------- faithful-f32-order scan: 1 block (1024 thr) per batch row ----------
__launch_bounds__(1024)
__global__ void srnn_scan(const float* __restrict__ x,
                          const float* __restrict__ Win,   // original [i][k] layout
                          const float* __restrict__ bin_p,
                          const float* __restrict__ bh1_p,
                          const float* __restrict__ b12_p,
                          const float* __restrict__ bh2_p,
                          const float* __restrict__ Wh1, int h1j, int h1i,
                          const float* __restrict__ W12m, int c12j, int c12i,
                          const float* __restrict__ Wh2, int h2j, int h2i,
                          const float* __restrict__ Wo,  int woj, int woi,
                          const float* __restrict__ bo_p,
                          float* __restrict__ out) {
  __shared__ float win_lds[N_IN * H];              // WinT[k][i], 128 KB
  __shared__ float xs[2][N_IN];
  __shared__ float xw[H], h1d[H], h2d[H], c12[H];
  __shared__ unsigned long long s1m[4], s2m[4];

  const int tid = (int)threadIdx.x;
  const int g   = tid >> 8;        // group 0..3
  const int i   = tid & 255;
  const int b   = (int)blockIdx.x;

  // Stage W_in into LDS transposed: win_lds[k*256 + i] = W_in[i*128 + k].
  // Coalesced global reads; LDS scatter writes (one-time cost).
  for (int q = tid; q < H * N_IN; q += 1024) {
    int i2 = q >> 7, k = q & (N_IN - 1);
    win_lds[k * H + i2] = Win[q];
  }

  // Per-role constants (hoisted loads)
  const float bin_i = (tid < H) ? bin_p[i] : 0.f;
  const float bh1_i = (tid < H) ? bh1_p[i] : 0.f;
  const float b12_i = (tid < H) ? b12_p[i] : 0.f;
  const float bh2_i = (tid < H) ? bh2_p[i] : 0.f;
  const float bo_o  = (g == 3 && i < N_OUT) ? bo_p[i] : 0.f;

  if (tid < 4) s1m[tid] = 0ull;
  else if (tid < 8) s2m[tid - 4] = 0ull;
  if (tid < N_IN) xs[0][tid] = x[(size_t)b * (T_STEPS * N_IN) + tid];

  float m1 = 0.f, m2 = 0.f, acc = 0.f;

  __syncthreads();

  for (int t = 0; t < T_STEPS; ++t) {
    const int cur = t & 1;

    // ---- Phase 1: x-dot | h1-gather | h2-gather | readout(t-1) + x-prefetch
    if (g == 0) {
      // Sequential k=0..127, single accumulator, FMA — numpy per-element order.
      float a = 0.f;
#pragma unroll 16
      for (int k = 0; k < N_IN; ++k)
        a = fmaf(xs[cur][k], win_lds[k * H + i], a);
      xw[i] = a;
    } else if (g == 1) {
      h1d[i] = walk16(s1m, Wh1, h1j, h1i, i);
    } else if (g == 2) {
      h2d[i] = walk16(s2m, Wh2, h2j, h2i, i);
    } else {
      if (i < N_OUT) {
        if (t - 1 >= WARM) {                 // readout for step t-1 (s2m = s2(t-1))
          float d = walk16(s2m, Wo, woj, woi, i);
          acc = acc + (d + bo_o);            // np order: (dot + b_out), then acc+
        }
      } else if (i >= 128 && t + 1 < T_STEPS) {
        int k = i - 128;
        xs[cur ^ 1][k] = x[(size_t)b * (T_STEPS * N_IN) + (size_t)(t + 1) * N_IN + k];
      }
    }
    __syncthreads();

    // ---- Phase 2: layer-1 membrane + spike (left-to-right np chain)
    if (tid < H) {
      float u1 = 0.9f * m1;
      u1 = u1 + xw[i];
      u1 = u1 + bin_i;
      u1 = u1 + h1d[i];
      u1 = u1 + bh1_i;
      bool sp = (u1 - 1.0f) > 0.0f;
      m1 = u1 - (sp ? 1.0f : 0.0f);
      unsigned long long bm = __ballot(sp);
      if ((tid & 63) == 0) s1m[tid >> 6] = bm;
    }
    __syncthreads();

    // ---- Phase 3: W_12 gather with SAME-step s1
    if (tid < H) c12[i] = walk16(s1m, W12m, c12j, c12i, i);
    __syncthreads();

    // ---- Phase 4: layer-2 membrane + spike
    if (tid < H) {
      float u2 = 0.9f * m2;
      u2 = u2 + c12[i];
      u2 = u2 + b12_i;
      u2 = u2 + h2d[i];
      u2 = u2 + bh2_i;
      bool sp = (u2 - 1.0f) > 0.0f;
      m2 = u2 - (sp ? 1.0f : 0.0f);
      unsigned long long bm = __ballot(sp);
      if ((tid & 63) == 0) s2m[tid >> 6] = bm;
    }
    __syncthreads();
  }

  // ---- final readout for t = 1023, then output
  if (g == 3 && i < N_OUT) {
    float d = walk16(s2m, Wo, woj, woi, i);
    acc = acc + (d + bo_o);
    out[(size_t)b * N_OUT + i] = acc / 1014.0f;   // f32 divide, like np
  }
}

// ---------- launch ----------
extern "C" void kernel_launch(void* const* d_in, const int* in_sizes, int n_in,
                              void* d_out, int out_size, void* d_ws, size_t ws_size,
                              hipStream_t stream) {
  const float* x     = (const float*)d_in[0];
  const float* W_in  = (const float*)d_in[1];
  const float* b_in  = (const float*)d_in[2];
  const float* W_h1  = (const float*)d_in[3];
  const float* b_h1  = (const float*)d_in[4];
  const float* W_12  = (const float*)d_in[5];
  const float* b_12  = (const float*)d_in[6];
  const float* W_h2  = (const float*)d_in[7];
  const float* b_h2  = (const float*)d_in[8];
  const float* W_out = (const float*)d_in[9];
  const float* b_out = (const float*)d_in[10];
  float* out = (float*)d_out;
  float* wsf = (float*)d_ws;

  const int total = 3 * H * H + H * N_OUT;            // 212992 floats
  const bool use_t = (ws_size >= (size_t)total * sizeof(float));

  const float *Wh1A, *W12A, *Wh2A, *WoA;
  int h1j, h1i, c12j, c12i, h2j, h2i, woj, woi;
  if (use_t) {
    srnn_prep<<<total / 256, 256, 0, stream>>>(W_h1, W_12, W_h2, W_out, wsf);
    Wh1A = wsf;                      h1j = H;  h1i = 1;    // Wh1T[j][i]
    W12A = wsf + (size_t)H * H;      c12j = H; c12i = 1;
    Wh2A = wsf + (size_t)2 * H * H;  h2j = H;  h2i = 1;
    WoA  = wsf + (size_t)3 * H * H;  woj = N_OUT; woi = 1; // WoutT[j][o]
  } else {
    Wh1A = W_h1;   h1j = 1;  h1i = H;                      // original layouts
    W12A = W_12;   c12j = 1; c12i = H;
    Wh2A = W_h2;   h2j = 1;  h2i = H;
    WoA  = W_out;  woj = 1;  woi = H;
  }

  srnn_scan<<<256, 1024, 0, stream>>>(x, W_in,
                                      b_in, b_h1, b_12, b_h2,
                                      Wh1A, h1j, h1i, W12A, c12j, c12i,
                                      Wh2A, h2j, h2i, WoA, woj, woi,
                                      b_out, out);
}